// Round 7
// baseline (111.049 us; speedup 1.0000x reference)
//
#include <hip/hip_runtime.h>
#include <hip/hip_bf16.h>

#define BT    8192      // B*T tokens (4*2048)
#define SEQ_T 2048
#define DIN   1024
#define NH    16
#define NK    8
#define DH    64
#define DO    64

typedef __bf16 bf16;
typedef __attribute__((ext_vector_type(8))) __bf16 bf16x8;
typedef __attribute__((ext_vector_type(4))) __bf16 bf16x4;
typedef __attribute__((ext_vector_type(4))) float floatx4;

// ---------------------------------------------------------------------------
// Kernel 1: (a) scores_t[k][token] = phi[t,k] + x[token,:]·diag[k,:]  (fp32)
//           4 tokens/wave -> each diag float4 load feeds 4 tokens (kills the
//           L1-BW bound of 1-tok/wave). xh copy is GONE (moe reads x fp32).
//           (b) wt[h*8+k][o][i] = bf16(W[h][k][i][o]) via LDS transpose.
// ---------------------------------------------------------------------------
__global__ __launch_bounds__(256) void prep_kernel(
    const float* __restrict__ x, const float* __restrict__ weight,
    const float* __restrict__ diag, const float* __restrict__ phi,
    float* __restrict__ scores_t, bf16* __restrict__ wt)
{
  int blk = blockIdx.x, tid = threadIdx.x;
  if (blk < BT / 16) {
    // ---- scores: 4 waves/block, 4 tokens/wave ----
    int wave = tid >> 6, lane = tid & 63;
    int tok = blk * 16 + wave * 4;
    const floatx4* dg = (const floatx4*)diag;
    float acc[4][NK];
#pragma unroll
    for (int j = 0; j < 4; j++)
#pragma unroll
      for (int k = 0; k < NK; k++) acc[j][k] = 0.f;
#pragma unroll
    for (int it = 0; it < 4; it++) {
      floatx4 xv[4];
#pragma unroll
      for (int j = 0; j < 4; j++)
        xv[j] = ((const floatx4*)(x + (size_t)(tok + j) * DIN))[it * 64 + lane];
#pragma unroll
      for (int k = 0; k < NK; k++) {
        floatx4 dv = dg[k * 256 + it * 64 + lane];
#pragma unroll
        for (int j = 0; j < 4; j++)
          acc[j][k] = fmaf(xv[j][0], dv[0], fmaf(xv[j][1], dv[1],
                      fmaf(xv[j][2], dv[2], fmaf(xv[j][3], dv[3], acc[j][k]))));
      }
    }
#pragma unroll
    for (int j = 0; j < 4; j++)
#pragma unroll
      for (int k = 0; k < NK; k++) {
        float v = acc[j][k];
#pragma unroll
        for (int off = 32; off >= 1; off >>= 1) v += __shfl_xor(v, off, 64);
        acc[j][k] = v;
      }
    if (lane == 0) {
#pragma unroll
      for (int j = 0; j < 4; j++) {
        int t = (tok + j) & (SEQ_T - 1);
#pragma unroll
        for (int k = 0; k < NK; k++)
          scores_t[(size_t)k * BT + tok + j] = phi[t * NK + k] + acc[j][k];
      }
    }
  } else {
    // ---- weight transpose: one (h,k) 64x64 tile per block, coalesced ----
    __shared__ bf16 tile[64 * 68];
    int hk = blk - BT / 16;
    const float* wsrc = weight + (size_t)hk * DH * DO;
#pragma unroll
    for (int it = 0; it < 4; it++) {
      int idx = it * 1024 + tid * 4;
      int i = idx >> 6, o = idx & 63;
      floatx4 v = *(const floatx4*)(wsrc + idx);
#pragma unroll
      for (int r = 0; r < 4; r++)
        tile[(o + r) * 68 + i] = (bf16)v[r];
    }
    __syncthreads();
#pragma unroll
    for (int it = 0; it < 4; it++) {
      int idx = it * 1024 + tid * 4;
      int o2 = idx >> 6, i2 = idx & 63;
      bf16x4 v = *(const bf16x4*)&tile[o2 * 68 + i2];
      *(bf16x4*)(wt + (size_t)hk * 4096 + idx) = v;
    }
  }
}

// ---------------------------------------------------------------------------
// Kernel 2 (v7): persistent multi-tile blocks. Grid = 16h x 2nh x 16slots =
// 512 = 2 blocks/CU at 64 KB LDS (W-half 32 KB staged ONCE + x double-buffer
// 2x16 KB bf16). Each block runs 4 token-group iterations: loads for tile
// i+1 are issued at iter start (a full compute-phase before the barrier that
// drains them), x is read directly as fp32 and converted during staging
// (xh intermediate eliminated), scores come from global (L2-hot broadcast).
// XOR chunk swizzle keeps every ds_read_b128 2-way-aliased (free, m136).
// ---------------------------------------------------------------------------
__global__ __launch_bounds__(256, 2) void moe_kernel(
    const float* __restrict__ x, const bf16* __restrict__ wt,
    const float* __restrict__ scores_t, float* __restrict__ out)
{
  __shared__ bf16 wl[256 * 64];        // 32 KB: rows R = e*32 + o (nh half)
  __shared__ bf16 xl[2][128 * 64];     // 2 x 16 KB double buffer

  int bid = blockIdx.x;
  int h    = bid >> 5;                 // 16 heads
  int nh   = (bid >> 4) & 1;           // col half
  int slot = bid & 15;                 // 16 slots x 4 token-groups
  int tid = threadIdx.x, lane = tid & 63, w = tid >> 6;
  int l15 = lane & 15, q = lane >> 4;
  int mh = w >> 1, ns = w & 1;

  // ---- stage W half once: 2048 16-B chunks, XOR-swizzled ----
  {
    const bf16* wh = wt + ((size_t)h * NK * DO + nh * 32) * DH;
#pragma unroll
    for (int it = 0; it < 8; it++) {
      int idx = it * 256 + tid;               // 0..2047
      int R = idx >> 3, c = idx & 7;          // R = e*32 + o
      int e = R >> 5, o = R & 31;
      bf16x8 v = *(const bf16x8*)(wh + (size_t)e * DO * DH + o * 64 + c * 8);
      *(bf16x8*)(wl + R * 64 + (c ^ (R & 7)) * 8) = v;
    }
  }

  const float* xc = x + (size_t)h * DH;
  int g0 = slot * 4;

  // staging helpers: flat f = j*1024 + tid*4 covers the 128x64 tile
  floatx4 xv[8];
  {
    const float* base = xc + (size_t)(g0 * 128) * DIN;
#pragma unroll
    for (int j = 0; j < 8; j++) {
      int f = j * 1024 + tid * 4;
      xv[j] = *(const floatx4*)(base + (size_t)(f >> 6) * DIN + (f & 63));
    }
  }
#pragma unroll
  for (int j = 0; j < 8; j++) {
    int f = j * 1024 + tid * 4;
    int row = f >> 6, col = f & 63;
    bf16x4 c4;
    c4[0] = (bf16)xv[j][0]; c4[1] = (bf16)xv[j][1];
    c4[2] = (bf16)xv[j][2]; c4[3] = (bf16)xv[j][3];
    *(bf16x4*)(&xl[0][0] + row * 64 + ((col >> 3) ^ (row & 7)) * 8 + (col & 7)) = c4;
  }
  __syncthreads();

  // ---- B fragments from LDS (persist across all 4 iterations) ----
  bf16x8 b[NK][2];
#pragma unroll
  for (int e = 0; e < NK; e++) {
    int R = e * 32 + ns * 16 + l15;
#pragma unroll
    for (int ki = 0; ki < 2; ki++)
      b[e][ki] = *(const bf16x8*)(wl + R * 64 + ((ki * 4 + q) ^ (R & 7)) * 8);
  }

#pragma unroll
  for (int i = 0; i < 4; i++) {
    int g = g0 + i;
    // issue next tile's global loads NOW (they land during this compute)
    if (i < 3) {
      const float* base = xc + (size_t)((g + 1) * 128) * DIN;
#pragma unroll
      for (int j = 0; j < 8; j++) {
        int f = j * 1024 + tid * 4;
        xv[j] = *(const floatx4*)(base + (size_t)(f >> 6) * DIN + (f & 63));
      }
    }
    // ---- compute from xl[i&1] ----
    const bf16* xb = &xl[i & 1][0];
#pragma unroll
    for (int m = 0; m < 4; m++) {
      int row = mh * 64 + m * 16 + l15;
      bf16x8 a0 = *(const bf16x8*)(xb + row * 64 + ((q    ) ^ (row & 7)) * 8);
      bf16x8 a1 = *(const bf16x8*)(xb + row * 64 + ((q + 4) ^ (row & 7)) * 8);
      floatx4 y = (floatx4){0.f, 0.f, 0.f, 0.f};
      int sbase = g * 128 + mh * 64 + m * 16 + q * 4;
#pragma unroll
      for (int e = 0; e < NK; e++) {
        floatx4 s4 = *(const floatx4*)(scores_t + (size_t)e * BT + sbase);
        floatx4 z = (floatx4){0.f, 0.f, 0.f, 0.f};
        z = __builtin_amdgcn_mfma_f32_16x16x32_bf16(a0, b[e][0], z, 0, 0, 0);
        z = __builtin_amdgcn_mfma_f32_16x16x32_bf16(a1, b[e][1], z, 0, 0, 0);
        y += s4 * z;
      }
      float* op = out + (size_t)(g * 128 + mh * 64 + m * 16 + q * 4) * (NH * DO)
                      + h * DO + nh * 32 + ns * 16 + l15;
#pragma unroll
      for (int r = 0; r < 4; r++)
        op[(size_t)r * (NH * DO)] = y[r];
    }
    // ---- convert+write next tile, then barrier (drains loads+writes) ----
    if (i < 3) {
      bf16* xn = &xl[(i + 1) & 1][0];
#pragma unroll
      for (int j = 0; j < 8; j++) {
        int f = j * 1024 + tid * 4;
        int row = f >> 6, col = f & 63;
        bf16x4 c4;
        c4[0] = (bf16)xv[j][0]; c4[1] = (bf16)xv[j][1];
        c4[2] = (bf16)xv[j][2]; c4[3] = (bf16)xv[j][3];
        *(bf16x4*)(xn + row * 64 + ((col >> 3) ^ (row & 7)) * 8 + (col & 7)) = c4;
      }
      __syncthreads();
    }
  }
}

extern "C" void kernel_launch(void* const* d_in, const int* in_sizes, int n_in,
                              void* d_out, int out_size, void* d_ws, size_t ws_size,
                              hipStream_t stream) {
  const float* x      = (const float*)d_in[0];
  const float* weight = (const float*)d_in[1];
  const float* diag   = (const float*)d_in[2];
  const float* phi    = (const float*)d_in[3];
  float* out = (float*)d_out;

  // workspace: [0,1MiB) wt (bf16, transposed) | [2MiB) scores_t 256 KiB
  bf16*  wt       = (bf16*)d_ws;
  float* scores_t = (float*)((char*)d_ws + (2u << 20));

  // 512 score blocks (16 tokens each) + 128 weight-transpose blocks
  prep_kernel<<<BT / 16 + NH * NK, 256, 0, stream>>>(x, weight, diag, phi,
                                                     scores_t, wt);
  // 16 heads x 2 col-halves x 16 slots (4 token-groups each)
  moe_kernel<<<NH * 2 * 16, 256, 0, stream>>>(x, wt, scores_t, out);
}